// Round 1
// baseline (51.769 us; speedup 1.0000x reference)
//
#include <hip/hip_runtime.h>
#include <math.h>

#define BB 32
#define HH 512
#define WW 512
#define CC 3

// vector elements: 4 pixels along w per thread-iteration
constexpr int W4 = WW / 4;                 // 128
constexpr int NV = BB * HH * W4;           // 2,097,152
constexpr long long NPIX = (long long)BB * HH * WW;  // 8,388,608

__global__ __launch_bounds__(256) void edge_loss_kernel(
    const float* __restrict__ pred,
    const int* __restrict__ tgt,
    double* __restrict__ acc)
{
    float sum = 0.0f;
    const int stride = gridDim.x * blockDim.x;

    for (int v = blockIdx.x * blockDim.x + threadIdx.x; v < NV; v += stride) {
        const int w4 = v & (W4 - 1);        // 0..127
        const int hb = v >> 7;
        const int h  = hb & (HH - 1);
        const int b  = hb >> 9;
        const int w  = w4 << 2;

        const int tbase = (b * HH + h) * WW + w;

        // center targets (4 pixels)
        const int4 tc = *reinterpret_cast<const int4*>(tgt + tbase);
        int t[4] = { tc.x, tc.y, tc.z, tc.w };

        // up/down rows
        const bool hasu = (h > 0);
        const bool hasd = (h < HH - 1);
        int4 tu = make_int4(0, 0, 0, 0);
        int4 td = make_int4(0, 0, 0, 0);
        if (hasu) tu = *reinterpret_cast<const int4*>(tgt + tbase - WW);
        if (hasd) td = *reinterpret_cast<const int4*>(tgt + tbase + WW);
        int tuv[4] = { tu.x, tu.y, tu.z, tu.w };
        int tdv[4] = { td.x, td.y, td.z, td.w };

        // left/right scalars at the vector edges
        const bool hasl = (w > 0);
        const bool hasr = (w + 4 < WW);
        const int tl = hasl ? tgt[tbase - 1] : 0;
        const int tr = hasr ? tgt[tbase + 4] : 0;

        // predictions: 3 classes, float4 each
        const size_t pbase = ((size_t)b * CC * HH + (size_t)h) * WW + w;
        const float4 p0 = *reinterpret_cast<const float4*>(pred + pbase);
        const float4 p1 = *reinterpret_cast<const float4*>(pred + pbase + (size_t)HH * WW);
        const float4 p2 = *reinterpret_cast<const float4*>(pred + pbase + 2 * (size_t)HH * WW);
        float c0[4] = { p0.x, p0.y, p0.z, p0.w };
        float c1[4] = { p1.x, p1.y, p1.z, p1.w };
        float c2[4] = { p2.x, p2.y, p2.z, p2.w };

        #pragma unroll
        for (int i = 0; i < 4; ++i) {
            int dil = t[i], ero = t[i];
            // up
            if (hasu) { dil = max(dil, tuv[i]); ero = min(ero, tuv[i]); }
            // down
            if (hasd) { dil = max(dil, tdv[i]); ero = min(ero, tdv[i]); }
            // left
            {
                int lv; bool ok;
                if (i == 0) { lv = tl; ok = hasl; }
                else        { lv = t[i - 1]; ok = true; }
                if (ok) { dil = max(dil, lv); ero = min(ero, lv); }
            }
            // right
            {
                int rv; bool ok;
                if (i == 3) { rv = tr; ok = hasr; }
                else        { rv = t[i + 1]; ok = true; }
                if (ok) { dil = max(dil, rv); ero = min(ero, rv); }
            }
            const int edge = dil ^ ero;

            // 3-class log-softmax CE
            const float a = c0[i], bq = c1[i], cq = c2[i];
            const float m = fmaxf(a, fmaxf(bq, cq));
            const float lse = m + logf(expf(a - m) + expf(bq - m) + expf(cq - m));
            const float pt = (t[i] == 0) ? a : ((t[i] == 1) ? bq : cq);
            const float ce = lse - pt;
            sum += ce * (1.0f + 2.0f * (float)edge);
        }
    }

    // wave-level reduce (64 lanes)
    #pragma unroll
    for (int off = 32; off > 0; off >>= 1)
        sum += __shfl_down(sum, off, 64);

    __shared__ float wsum[4];  // 256 threads -> 4 waves
    const int lane = threadIdx.x & 63;
    const int wid  = threadIdx.x >> 6;
    if (lane == 0) wsum[wid] = sum;
    __syncthreads();
    if (threadIdx.x == 0) {
        const float s = wsum[0] + wsum[1] + wsum[2] + wsum[3];
        atomicAdd(acc, (double)s);
    }
}

__global__ void finalize_kernel(const double* __restrict__ acc, float* __restrict__ out) {
    out[0] = (float)(acc[0] / (double)NPIX);
}

extern "C" void kernel_launch(void* const* d_in, const int* in_sizes, int n_in,
                              void* d_out, int out_size, void* d_ws, size_t ws_size,
                              hipStream_t stream) {
    const float* pred = (const float*)d_in[0];
    const int*   tgt  = (const int*)d_in[1];
    double* acc = (double*)d_ws;
    float*  out = (float*)d_out;

    hipMemsetAsync(acc, 0, sizeof(double), stream);
    edge_loss_kernel<<<2048, 256, 0, stream>>>(pred, tgt, acc);
    finalize_kernel<<<1, 1, 0, stream>>>(acc, out);
}

// Round 2
// 32.212 us; speedup vs baseline: 1.6071x; 1.6071x over previous
//
#include <hip/hip_runtime.h>

#define BB 32
#define HH 512
#define WW 512

constexpr int PLANE = HH * WW;                         // 262144
constexpr long long NPIX = (long long)BB * HH * WW;    // 8,388,608
constexpr int BLOCK = 256;
constexpr int GRID = (BB * HH * 64) / BLOCK;           // 4096 blocks; 1 wave = 1 row

__global__ __launch_bounds__(256) void edge_loss_kernel(
    const float* __restrict__ pred,
    const int* __restrict__ tgt,
    double* __restrict__ partial)
{
    const int tid  = blockIdx.x * BLOCK + threadIdx.x;
    const int lane = threadIdx.x & 63;
    const int row  = tid >> 6;            // 0..16383 (b*512 + h)
    const int h    = row & (HH - 1);
    const int b    = row >> 9;
    const int w    = lane << 3;           // 0..504, 8 px per thread

    const int tbase = row * WW + w;

    // center 8 targets
    const int4 c0 = *reinterpret_cast<const int4*>(tgt + tbase);
    const int4 c1 = *reinterpret_cast<const int4*>(tgt + tbase + 4);
    int tc[8] = { c0.x, c0.y, c0.z, c0.w, c1.x, c1.y, c1.z, c1.w };

    const bool hasu = (h > 0);
    const bool hasd = (h < HH - 1);
    int tu[8], td[8];
    if (hasu) {
        const int4 u0 = *reinterpret_cast<const int4*>(tgt + tbase - WW);
        const int4 u1 = *reinterpret_cast<const int4*>(tgt + tbase - WW + 4);
        tu[0]=u0.x; tu[1]=u0.y; tu[2]=u0.z; tu[3]=u0.w;
        tu[4]=u1.x; tu[5]=u1.y; tu[6]=u1.z; tu[7]=u1.w;
    }
    if (hasd) {
        const int4 d0 = *reinterpret_cast<const int4*>(tgt + tbase + WW);
        const int4 d1 = *reinterpret_cast<const int4*>(tgt + tbase + WW + 4);
        td[0]=d0.x; td[1]=d0.y; td[2]=d0.z; td[3]=d0.w;
        td[4]=d1.x; td[5]=d1.y; td[6]=d1.z; td[7]=d1.w;
    }

    // cross-lane left/right neighbors (wave spans the full row)
    const int lshf = __shfl_up(tc[7], 1, 64);    // lane 0: invalid -> masked below
    const int rshf = __shfl_down(tc[0], 1, 64);  // lane 63: invalid -> masked below

    // predictions: 3 class planes, 2x float4 each
    const float* p0 = pred + (size_t)(b * 3) * PLANE + (size_t)h * WW + w;
    const float4 a0 = *reinterpret_cast<const float4*>(p0);
    const float4 a1 = *reinterpret_cast<const float4*>(p0 + 4);
    const float4 b0 = *reinterpret_cast<const float4*>(p0 + PLANE);
    const float4 b1 = *reinterpret_cast<const float4*>(p0 + PLANE + 4);
    const float4 q0 = *reinterpret_cast<const float4*>(p0 + 2 * PLANE);
    const float4 q1 = *reinterpret_cast<const float4*>(p0 + 2 * PLANE + 4);
    const float A[8] = { a0.x, a0.y, a0.z, a0.w, a1.x, a1.y, a1.z, a1.w };
    const float B[8] = { b0.x, b0.y, b0.z, b0.w, b1.x, b1.y, b1.z, b1.w };
    const float C[8] = { q0.x, q0.y, q0.z, q0.w, q1.x, q1.y, q1.z, q1.w };

    const float L2E = 1.4426950408889634f;
    const float LN2 = 0.6931471805599453f;
    float sum = 0.0f;

    #pragma unroll
    for (int i = 0; i < 8; ++i) {
        int d = tc[i], e = tc[i];
        if (hasu) { d = max(d, tu[i]); e = min(e, tu[i]); }  // wave-uniform branch
        if (hasd) { d = max(d, td[i]); e = min(e, td[i]); }
        int lv_d, lv_e, rv_d, rv_e;
        if (i == 0) { lv_d = (lane > 0)  ? lshf : 0; lv_e = (lane > 0)  ? lshf : 255; }
        else        { lv_d = lv_e = tc[i - 1]; }
        if (i == 7) { rv_d = (lane < 63) ? rshf : 0; rv_e = (lane < 63) ? rshf : 255; }
        else        { rv_d = rv_e = tc[i + 1]; }
        d = max(d, max(lv_d, rv_d));
        e = min(e, min(lv_e, rv_e));
        const int edge = d ^ e;

        const float pa = A[i], pb = B[i], pc = C[i];
        const float s = __builtin_amdgcn_exp2f(pa * L2E)
                      + __builtin_amdgcn_exp2f(pb * L2E)
                      + __builtin_amdgcn_exp2f(pc * L2E);
        const float lse = LN2 * __builtin_amdgcn_logf(s);
        const float pt  = (tc[i] == 0) ? pa : ((tc[i] == 1) ? pb : pc);
        const float wgt = fmaf(2.0f, (float)edge, 1.0f);
        sum = fmaf(lse - pt, wgt, sum);
    }

    // wave reduce (64 lanes) then block reduce
    #pragma unroll
    for (int off = 32; off; off >>= 1)
        sum += __shfl_down(sum, off, 64);

    __shared__ float wsum[4];
    if (lane == 0) wsum[threadIdx.x >> 6] = sum;
    __syncthreads();
    if (threadIdx.x == 0)
        partial[blockIdx.x] = (double)(wsum[0] + wsum[1] + wsum[2] + wsum[3]);
}

__global__ __launch_bounds__(256) void finalize_kernel(
    const double* __restrict__ partial, float* __restrict__ out)
{
    double s = 0.0;
    for (int i = threadIdx.x; i < GRID; i += 256) s += partial[i];
    #pragma unroll
    for (int off = 32; off; off >>= 1)
        s += __shfl_down(s, off, 64);
    __shared__ double wsum[4];
    const int lane = threadIdx.x & 63;
    if (lane == 0) wsum[threadIdx.x >> 6] = s;
    __syncthreads();
    if (threadIdx.x == 0)
        out[0] = (float)((wsum[0] + wsum[1] + wsum[2] + wsum[3]) / (double)NPIX);
}

extern "C" void kernel_launch(void* const* d_in, const int* in_sizes, int n_in,
                              void* d_out, int out_size, void* d_ws, size_t ws_size,
                              hipStream_t stream) {
    const float* pred = (const float*)d_in[0];
    const int*   tgt  = (const int*)d_in[1];
    double* partial = (double*)d_ws;          // 4096 * 8 B = 32 KiB
    float*  out     = (float*)d_out;

    edge_loss_kernel<<<GRID, BLOCK, 0, stream>>>(pred, tgt, partial);
    finalize_kernel<<<1, BLOCK, 0, stream>>>(partial, out);
}